// Round 3
// baseline (23143.121 us; speedup 1.0000x reference)
//
#include <hip/hip_runtime.h>
#include <hip/hip_bf16.h>

#define T_STEPS 2048
#define BATCH 32
#define DIN 512
#define HID 512
#define G4H 2048
#define NWG 64      // worker WGs
#define GRID 256    // workers + ballast (hold SCLK up on idle CUs)
#define SLICE 8
#define THREADS 256
#define HPAIRS (BATCH * HID / 2)  // 8192 u64 per tag buffer

typedef __attribute__((ext_vector_type(8))) short short8;
typedef __attribute__((ext_vector_type(4))) float floatx4;
typedef __attribute__((ext_vector_type(4))) unsigned int uintx4;
typedef unsigned long long ull;

__device__ __forceinline__ ushort f2bf(float f) {
  return __builtin_bit_cast(ushort, __float2bfloat16(f));
}

// One-shot prep: bf16 weights, combined bias, tagged h0 buffers, kill flag.
// tagbuf[2][32][256] u64: (h(2p+1)<<48)|(h(2p)<<32)|tag. Buffer 0 = h0 (tag 0),
// buffer 1 = never-matching tag so step t=1 polls until real data lands.
__global__ void prep_kernel(const float* __restrict__ wih, const float* __restrict__ whh,
                            const float* __restrict__ bih, const float* __restrict__ bhh,
                            const float* __restrict__ h0,
                            ushort* __restrict__ wihb, ushort* __restrict__ whhb,
                            float* __restrict__ bias, ull* __restrict__ tagbuf,
                            unsigned* __restrict__ kill) {
  int i = blockIdx.x * blockDim.x + threadIdx.x;
  const int NW = G4H * DIN;
  if (i < NW) { wihb[i] = f2bf(wih[i]); whhb[i] = f2bf(whh[i]); }
  if (i < G4H) bias[i] = bih[i] + bhh[i];
  if (i == 0) kill[0] = 0u;
  if (i < HPAIRS) {
    int b = i >> 8, p = i & 255;
    ull ev = (ull)f2bf(h0[b * HID + 2 * p]);
    ull od = (ull)f2bf(h0[b * HID + 2 * p + 1]);
    tagbuf[i] = (od << 48) | (ev << 32);   // tag 0
    tagbuf[HPAIRS + i] = 0xFFFFFFFFull;    // bogus tag (tags used are 0..T_STEPS)
  }
}

__global__ void cvtx_kernel(const float* __restrict__ x, ushort* __restrict__ xb) {
  const size_t N = (size_t)T_STEPS * BATCH * DIN;
  size_t stride = (size_t)gridDim.x * blockDim.x * 4;
  for (size_t idx = ((size_t)blockIdx.x * blockDim.x + threadIdx.x) * 4; idx < N; idx += stride) {
    float4 f = *reinterpret_cast<const float4*>(x + idx);
    ushort4 u;
    u.x = f2bf(f.x); u.y = f2bf(f.y); u.z = f2bf(f.z); u.w = f2bf(f.w);
    *reinterpret_cast<ushort4*>(xb + idx) = u;
  }
}

// x-part MFMA for timestep t. OPERAND-SWAPPED: mfma(W_frag, x_frag) so the
// C tile is [gate-row][batch-col]; lane (quad,n16) ends up owning all 4 gates
// (acc[0..3]) for batch brow=r*16+n16, hidden ecol=g*8+cc*4+quad.
template <bool XB>
__device__ __forceinline__ floatx4 xpart(const float* __restrict__ x,
                                         const ushort* __restrict__ xb,
                                         int t, int brow, int quad,
                                         const short8* wih_r) {
  floatx4 a = {0.f, 0.f, 0.f, 0.f};
  floatx4 b = {0.f, 0.f, 0.f, 0.f};
  if (XB) {
    const ushort* xt = xb + ((size_t)t * BATCH + brow) * DIN + quad * 8;
#pragma unroll
    for (int kb = 0; kb < 16; ++kb) {
      short8 a0 = *reinterpret_cast<const short8*>(xt + kb * 32);
      if (kb & 1)
        b = __builtin_amdgcn_mfma_f32_16x16x32_bf16(wih_r[kb], a0, b, 0, 0, 0);
      else
        a = __builtin_amdgcn_mfma_f32_16x16x32_bf16(wih_r[kb], a0, a, 0, 0, 0);
    }
  } else {
    const float* xt = x + ((size_t)t * BATCH + brow) * DIN + quad * 8;
#pragma unroll
    for (int kb = 0; kb < 16; ++kb) {
      const float4* xp = reinterpret_cast<const float4*>(xt + kb * 32);
      float4 f0 = xp[0], f1 = xp[1];
      short8 a0;
      a0[0] = (short)f2bf(f0.x); a0[1] = (short)f2bf(f0.y);
      a0[2] = (short)f2bf(f0.z); a0[3] = (short)f2bf(f0.w);
      a0[4] = (short)f2bf(f1.x); a0[5] = (short)f2bf(f1.y);
      a0[6] = (short)f2bf(f1.z); a0[7] = (short)f2bf(f1.w);
      if (kb & 1)
        b = __builtin_amdgcn_mfma_f32_16x16x32_bf16(wih_r[kb], a0, b, 0, 0, 0);
      else
        a = __builtin_amdgcn_mfma_f32_16x16x32_bf16(wih_r[kb], a0, a, 0, 0, 0);
    }
  }
  return a + b;
}

// Persistent LSTM. Worker WGs (g<NWG): identical protocol to round 2 —
// self-tagged u64 h exchange (2 bf16 + 32-bit step tag per atomic quantum),
// operand-swapped MFMA, no LDS, no barriers. Ballast WGs (g>=NWG): dependent
// FMA spin on otherwise-idle CUs to hold SCLK at max (DPM downclock theory);
// exit on kill flag set by worker WG0 at the end. Safe under plain launch:
// GRID=256 blocks at launch_bounds(256,1) => 1 block/CU, all co-resident.
template <bool XB>
__global__ __launch_bounds__(THREADS, 1) void lstm_kernel(
    const float* __restrict__ x, const ushort* __restrict__ xb,
    const float* __restrict__ c0,
    const ushort* __restrict__ wihb, const ushort* __restrict__ whhb,
    const float* __restrict__ bias, ull* __restrict__ tagbuf,
    float* __restrict__ out, unsigned* __restrict__ kill) {
  const int g = blockIdx.x;
  const int tid = threadIdx.x;

  if (g >= NWG) {
    // ---- ballast: keep the chip busy so DPM holds clocks high ----
    float acc[8];
#pragma unroll
    for (int i = 0; i < 8; ++i) acc[i] = (float)(tid + i) * 1.000001f + 0.5f;
    for (;;) {
      unsigned k = __hip_atomic_load(kill, __ATOMIC_RELAXED, __HIP_MEMORY_SCOPE_AGENT);
      if (k) break;
      for (int it = 0; it < 1024; ++it) {
#pragma unroll
        for (int i = 0; i < 8; ++i)
          acc[i] = __builtin_fmaf(acc[i], 1.0000001f, 1.0e-7f);
      }
    }
#pragma unroll
    for (int i = 0; i < 8; ++i) asm volatile("" ::"v"(acc[i]));
    return;
  }

  const int lane = tid & 63;
  const int wave = tid >> 6;
  const int r = wave & 1;        // batch half
  const int cc = wave >> 1;      // column tile
  const int n16 = lane & 15;
  const int quad = lane >> 4;
  const int brow = r * 16 + n16;                         // batch row: loads AND ownership
  const int j = cc * 16 + n16;                           // WG-local gate col 0..31
  const int wrow = (j & 3) * HID + g * SLICE + (j >> 2); // global gate row

  const int ecol = g * SLICE + cc * 4 + quad;            // owned hidden col
  float c_val = c0[brow * HID + ecol];
  const float bi = bias[ecol];
  const float bf_ = bias[HID + ecol];
  const float bg = bias[2 * HID + ecol];
  const float bo = bias[3 * HID + ecol];

  // Weights resident in registers for the whole run.
  short8 wih_r[16], whh_r[16];
  {
    const ushort* wr = wihb + (size_t)wrow * DIN + quad * 8;
    const ushort* hr = whhb + (size_t)wrow * HID + quad * 8;
#pragma unroll
    for (int kb = 0; kb < 16; ++kb) {
      wih_r[kb] = *reinterpret_cast<const short8*>(wr + kb * 32);
      whh_r[kb] = *reinterpret_cast<const short8*>(hr + kb * 32);
    }
  }

  floatx4 acc0_cur = xpart<XB>(x, xb, 0, brow, quad, wih_r);

  float hlast = 0.f;
  for (int t = 0; t < T_STEPS; ++t) {
    // ---- poll tagged h(t); MFMA each 4-load group as it validates ----
    const ull* hb = tagbuf + (size_t)(t & 1) * HPAIRS + (size_t)brow * (HID / 2) + quad * 4;
    const unsigned tagt = (unsigned)t;
    floatx4 acc1a = {0.f, 0.f, 0.f, 0.f};
    floatx4 acc1b = {0.f, 0.f, 0.f, 0.f};
    unsigned done = 0;
    for (;;) {
      ull d[16][4];
#pragma unroll
      for (int kb = 0; kb < 16; ++kb) {
        if (!(done & (1u << kb))) {
#pragma unroll
          for (int m = 0; m < 4; ++m)
            d[kb][m] = __hip_atomic_load(hb + kb * 16 + m, __ATOMIC_RELAXED,
                                         __HIP_MEMORY_SCOPE_AGENT);
        }
      }
#pragma unroll
      for (int kb = 0; kb < 16; ++kb) {
        if (!(done & (1u << kb))) {
          bool ok = ((unsigned)d[kb][0] == tagt) & ((unsigned)d[kb][1] == tagt) &
                    ((unsigned)d[kb][2] == tagt) & ((unsigned)d[kb][3] == tagt);
          if (__all(ok)) {
            uintx4 pk;
            pk.x = (unsigned)(d[kb][0] >> 32);
            pk.y = (unsigned)(d[kb][1] >> 32);
            pk.z = (unsigned)(d[kb][2] >> 32);
            pk.w = (unsigned)(d[kb][3] >> 32);
            short8 hf = __builtin_bit_cast(short8, pk);
            if (kb & 1)
              acc1b = __builtin_amdgcn_mfma_f32_16x16x32_bf16(whh_r[kb], hf, acc1b, 0, 0, 0);
            else
              acc1a = __builtin_amdgcn_mfma_f32_16x16x32_bf16(whh_r[kb], hf, acc1a, 0, 0, 0);
            done |= (1u << kb);
          }
        }
      }
      if (done == 0xFFFFu) break;
      __builtin_amdgcn_s_sleep(1);
    }

    // ---- elementwise: this lane owns all 4 gates of (brow, ecol) ----
    float pi = acc0_cur[0] + acc1a[0] + acc1b[0] + bi;
    float pf = acc0_cur[1] + acc1a[1] + acc1b[1] + bf_;
    float pg = acc0_cur[2] + acc1a[2] + acc1b[2] + bg;
    float po = acc0_cur[3] + acc1a[3] + acc1b[3] + bo;
    float ig = 1.f / (1.f + __expf(-pi));
    float fg = 1.f / (1.f + __expf(-pf));
    float eg = __expf(2.f * pg);
    float gg = 1.f - 2.f / (eg + 1.f);      // tanh
    float og = 1.f / (1.f + __expf(-po));
    c_val = fg * c_val + ig * gg;
    float ec = __expf(2.f * c_val);
    float tc = 1.f - 2.f / (ec + 1.f);      // tanh(c)
    float h = og * tc;
    hlast = h;

    // ---- publish h(t+1): pair (even,odd) hidden + tag in one u64, no fence ----
    unsigned hu = (unsigned)f2bf(h);
    unsigned hpart = (unsigned)__shfl_xor((int)hu, 16);  // quad^1 -> ecol^1
    if ((quad & 1) == 0) {
      ull v = ((ull)hpart << 48) | ((ull)hu << 32) | (ull)(unsigned)(t + 1);
      ull* dst = tagbuf + (size_t)((t + 1) & 1) * HPAIRS +
                 (size_t)brow * (HID / 2) + (ecol >> 1);
      __hip_atomic_store(dst, v, __ATOMIC_RELAXED, __HIP_MEMORY_SCOPE_AGENT);
    }
    __atomic_signal_fence(__ATOMIC_SEQ_CST);  // keep the publish early (compiler-only)

    // ---- out[t]: pack 4 hidden cols to one dwordx4 on quad==0 lanes ----
    float h1 = __shfl_xor(h, 16);
    float h2 = __shfl_xor(h, 32);
    float h3 = __shfl_xor(h1, 32);
    if (quad == 0) {
      float4 o4 = make_float4(h, h1, h2, h3);
      *reinterpret_cast<float4*>(out + (size_t)t * (BATCH * HID) + brow * HID +
                                 g * SLICE + cc * 4) = o4;
    }

    // ---- x-part for t+1 (overlaps other WGs consuming our publish) ----
    const int tt = (t + 1 < T_STEPS) ? t + 1 : t;
    acc0_cur = xpart<XB>(x, xb, tt, brow, quad, wih_r);
  }
  // tail outputs: h_n, c_n
  out[(size_t)T_STEPS * BATCH * HID + brow * HID + ecol] = hlast;
  out[(size_t)T_STEPS * BATCH * HID + BATCH * HID + brow * HID + ecol] = c_val;

  // release the ballast
  if (g == 0 && tid == 0)
    __hip_atomic_store(kill, 1u, __ATOMIC_RELAXED, __HIP_MEMORY_SCOPE_AGENT);
}

extern "C" void kernel_launch(void* const* d_in, const int* in_sizes, int n_in,
                              void* d_out, int out_size, void* d_ws, size_t ws_size,
                              hipStream_t stream) {
  const float* x = (const float*)d_in[0];
  const float* h0 = (const float*)d_in[1];
  const float* c0 = (const float*)d_in[2];
  const float* w_ih = (const float*)d_in[3];
  const float* b_ih = (const float*)d_in[4];
  const float* w_hh = (const float*)d_in[5];
  const float* b_hh = (const float*)d_in[6];
  float* out = (float*)d_out;
  char* ws = (char*)d_ws;

  // workspace layout
  unsigned* kill = (unsigned*)ws;                         // 4 B
  float* bias = (float*)(ws + 1024);                      // 8 KB
  ushort* wihb = (ushort*)(ws + (16 << 10));              // 2 MB
  ushort* whhb = (ushort*)(ws + (16 << 10) + (2 << 20));  // 2 MB
  ull* tagbuf = (ull*)(ws + (16 << 10) + (4 << 20));      // 128 KB (2 tagged buffers)
  ushort* xb = (ushort*)(ws + (8 << 20));                 // 64 MB (optional)
  const size_t xb_bytes = (size_t)T_STEPS * BATCH * DIN * sizeof(ushort);
  const bool use_xb = ws_size >= ((size_t)(8 << 20) + xb_bytes);

  hipLaunchKernelGGL(prep_kernel, dim3(4096), dim3(256), 0, stream,
                     w_ih, w_hh, b_ih, b_hh, h0, wihb, whhb, bias, tagbuf, kill);

  if (use_xb) {
    hipLaunchKernelGGL(cvtx_kernel, dim3(8192), dim3(256), 0, stream, x, xb);
    void* args[] = {(void*)&x, (void*)&xb, (void*)&c0, (void*)&wihb, (void*)&whhb,
                    (void*)&bias, (void*)&tagbuf, (void*)&out, (void*)&kill};
    hipError_t e = hipLaunchCooperativeKernel(
        reinterpret_cast<void*>(&lstm_kernel<true>), dim3(GRID), dim3(THREADS),
        args, 0, stream);
    if (e != hipSuccess) {
      // Silent-rejection fallback: plain launch. 256 blocks at 1 block/CU on
      // 256 CUs are unconditionally co-resident, so the spin protocol is safe.
      hipLaunchKernelGGL(lstm_kernel<true>, dim3(GRID), dim3(THREADS), 0, stream,
                         x, xb, c0, wihb, whhb, bias, tagbuf, out, kill);
    }
  } else {
    void* args[] = {(void*)&x, (void*)&xb, (void*)&c0, (void*)&wihb, (void*)&whhb,
                    (void*)&bias, (void*)&tagbuf, (void*)&out, (void*)&kill};
    hipError_t e = hipLaunchCooperativeKernel(
        reinterpret_cast<void*>(&lstm_kernel<false>), dim3(GRID), dim3(THREADS),
        args, 0, stream);
    if (e != hipSuccess) {
      hipLaunchKernelGGL(lstm_kernel<false>, dim3(GRID), dim3(THREADS), 0, stream,
                         x, xb, c0, wihb, whhb, bias, tagbuf, out, kill);
    }
  }
}

// Round 4
// 20427.472 us; speedup vs baseline: 1.1329x; 1.1329x over previous
//
#include <hip/hip_runtime.h>
#include <hip/hip_bf16.h>

#define T_STEPS 2048
#define BATCH 32
#define DIN 512
#define HID 512
#define G4H 2048
#define NWG 16
#define SLICE 32
#define THREADS 512
#define HU32 (BATCH * HID / 2)   // 8192 u32 per h buffer
#define HULL (BATCH * HID / 4)   // 4096 u64 per h buffer

typedef __attribute__((ext_vector_type(8))) short short8;
typedef __attribute__((ext_vector_type(4))) float floatx4;
typedef unsigned long long ull;

__device__ __forceinline__ ushort f2bf(float f) {
  return __builtin_bit_cast(ushort, __float2bfloat16(f));
}

// One-shot prep: bf16 weights, combined bias, h0 into hg[0], flags=0.
// hg[2][32][512] bf16 stored as u32 pairs; buffer 1 needs no init (fully
// overwritten by step-0 publishes before any step-1 consumer reads it).
__global__ void prep_kernel(const float* __restrict__ wih, const float* __restrict__ whh,
                            const float* __restrict__ bih, const float* __restrict__ bhh,
                            const float* __restrict__ h0,
                            ushort* __restrict__ wihb, ushort* __restrict__ whhb,
                            float* __restrict__ bias, unsigned* __restrict__ hgu,
                            unsigned* __restrict__ flags) {
  int i = blockIdx.x * blockDim.x + threadIdx.x;
  const int NW = G4H * DIN;
  if (i < NW) { wihb[i] = f2bf(wih[i]); whhb[i] = f2bf(whh[i]); }
  if (i < G4H) bias[i] = bih[i] + bhh[i];
  if (i < NWG) flags[i] = 0u;
  if (i < HU32) {
    int b = i >> 8, cp = i & 255;
    unsigned lo = f2bf(h0[b * HID + 2 * cp]);
    unsigned hi = f2bf(h0[b * HID + 2 * cp + 1]);
    hgu[i] = lo | (hi << 16);
  }
}

__global__ void cvtx_kernel(const float* __restrict__ x, ushort* __restrict__ xb) {
  const size_t N = (size_t)T_STEPS * BATCH * DIN;
  size_t stride = (size_t)gridDim.x * blockDim.x * 4;
  for (size_t idx = ((size_t)blockIdx.x * blockDim.x + threadIdx.x) * 4; idx < N; idx += stride) {
    float4 f = *reinterpret_cast<const float4*>(x + idx);
    ushort4 u;
    u.x = f2bf(f.x); u.y = f2bf(f.y); u.z = f2bf(f.z); u.w = f2bf(f.w);
    *reinterpret_cast<ushort4*>(xb + idx) = u;
  }
}

// x-part MFMAs for timestep t, both batch halves. Operand-swapped
// mfma(W_frag, x_frag): D[gate-row][batch]; lane(n16,quad) ends up with all
// 4 gates (acc[0..3]) of (batch = half*16+n16, hidden ecol = g*32+wave*4+quad).
template <bool XB>
__device__ __forceinline__ void xpart2(const float* __restrict__ x,
                                       const ushort* __restrict__ xb,
                                       int t, int n16, int quad,
                                       const short8* wih_r,
                                       floatx4& o0, floatx4& o1) {
  floatx4 a0 = {0.f, 0.f, 0.f, 0.f};
  floatx4 a1 = {0.f, 0.f, 0.f, 0.f};
  if (XB) {
    const ushort* xt0 = xb + ((size_t)t * BATCH + n16) * DIN + quad * 8;
    const ushort* xt1 = xt0 + 16 * DIN;
#pragma unroll
    for (int kb = 0; kb < 16; ++kb) {
      short8 b0 = *reinterpret_cast<const short8*>(xt0 + kb * 32);
      short8 b1 = *reinterpret_cast<const short8*>(xt1 + kb * 32);
      a0 = __builtin_amdgcn_mfma_f32_16x16x32_bf16(wih_r[kb], b0, a0, 0, 0, 0);
      a1 = __builtin_amdgcn_mfma_f32_16x16x32_bf16(wih_r[kb], b1, a1, 0, 0, 0);
    }
  } else {
    const float* xt0 = x + ((size_t)t * BATCH + n16) * DIN + quad * 8;
    const float* xt1 = xt0 + 16 * DIN;
#pragma unroll
    for (int kb = 0; kb < 16; ++kb) {
      const float4* xp0 = reinterpret_cast<const float4*>(xt0 + kb * 32);
      const float4* xp1 = reinterpret_cast<const float4*>(xt1 + kb * 32);
      float4 f0 = xp0[0], f1 = xp0[1], g0 = xp1[0], g1 = xp1[1];
      short8 b0, b1;
      b0[0] = (short)f2bf(f0.x); b0[1] = (short)f2bf(f0.y);
      b0[2] = (short)f2bf(f0.z); b0[3] = (short)f2bf(f0.w);
      b0[4] = (short)f2bf(f1.x); b0[5] = (short)f2bf(f1.y);
      b0[6] = (short)f2bf(f1.z); b0[7] = (short)f2bf(f1.w);
      b1[0] = (short)f2bf(g0.x); b1[1] = (short)f2bf(g0.y);
      b1[2] = (short)f2bf(g0.z); b1[3] = (short)f2bf(g0.w);
      b1[4] = (short)f2bf(g1.x); b1[5] = (short)f2bf(g1.y);
      b1[6] = (short)f2bf(g1.z); b1[7] = (short)f2bf(g1.w);
      a0 = __builtin_amdgcn_mfma_f32_16x16x32_bf16(wih_r[kb], b0, a0, 0, 0, 0);
      a1 = __builtin_amdgcn_mfma_f32_16x16x32_bf16(wih_r[kb], b1, a1, 0, 0, 0);
    }
  }
  o0 = a0; o1 = a1;
}

// Persistent LSTM, 16 WGs x 512 threads (SLICE=32 hidden cols/WG, 8 waves).
// Per step: wave-poll 16 per-WG flags; WG cooperatively loads the 32KB h(t)
// ONCE via coalesced 8B agent loads (4K requests/WG vs 1M grid-wide before);
// stage into XOR-swizzled LDS (parity double-buffer); waves ds_read B-frags;
// 32 h-MFMA + 32 x-MFMA per wave; publish 2KB/WG packed u32 + flag after the
// barrier's implicit vmcnt drain (round-0-proven visibility path).
template <bool XB>
__global__ __launch_bounds__(THREADS, 1) void lstm_kernel(
    const float* __restrict__ x, const ushort* __restrict__ xb,
    const float* __restrict__ c0,
    const ushort* __restrict__ wihb, const ushort* __restrict__ whhb,
    const float* __restrict__ bias, unsigned* __restrict__ hgu,
    unsigned* __restrict__ flags, float* __restrict__ out) {
  const int g = blockIdx.x;
  const int tid = threadIdx.x;
  const int lane = tid & 63;
  const int wave = tid >> 6;     // 0..7
  const int n16 = lane & 15;
  const int quad = lane >> 4;

  // A-tile row m = n16 maps to (gate = m&3, colofs = m>>2):
  const int wrow = (n16 & 3) * HID + g * SLICE + wave * 4 + (n16 >> 2);
  const int ecol = g * SLICE + wave * 4 + quad;   // owned hidden col (both halves)

  float c_v0 = c0[n16 * HID + ecol];              // batch = n16
  float c_v1 = c0[(16 + n16) * HID + ecol];       // batch = 16+n16
  const float b_i = bias[ecol];
  const float b_f = bias[HID + ecol];
  const float b_g = bias[2 * HID + ecol];
  const float b_o = bias[3 * HID + ecol];

  // Weights resident in registers for the whole run (~128 VGPR).
  short8 wih_r[16], whh_r[16];
  {
    const ushort* wr = wihb + (size_t)wrow * DIN + quad * 8;
    const ushort* hr = whhb + (size_t)wrow * HID + quad * 8;
#pragma unroll
    for (int kb = 0; kb < 16; ++kb) {
      wih_r[kb] = *reinterpret_cast<const short8*>(wr + kb * 32);
      whh_r[kb] = *reinterpret_cast<const short8*>(hr + kb * 32);
    }
  }

  __shared__ __align__(16) char hlds[2][32 * 1024];  // 64 KB, parity dbuf
  const ull* hgq = reinterpret_cast<const ull*>(hgu);

  floatx4 x0, x1;
  xpart2<XB>(x, xb, 0, n16, quad, wih_r, x0, x1);

  float h_l0 = 0.f, h_l1 = 0.f;
  for (int t = 0; t < T_STEPS; ++t) {
    const int par = t & 1;
    // ---- wave-poll: lanes cover the 16 WG flags 4x; __all => all >= t ----
    if (t) {
      const unsigned tgt = (unsigned)t;
      for (;;) {
        unsigned f = __hip_atomic_load(&flags[lane & 15], __ATOMIC_RELAXED,
                                       __HIP_MEMORY_SCOPE_AGENT);
        if (__all(f >= tgt)) break;
        __builtin_amdgcn_s_sleep(1);
      }
    }
    __atomic_signal_fence(__ATOMIC_ACQUIRE);

    // ---- cooperative stage: 8 coalesced u64 agent-loads/thread -> LDS ----
    {
      const ull* src = hgq + (size_t)par * HULL;
      ull d[8];
#pragma unroll
      for (int m = 0; m < 8; ++m)
        d[m] = __hip_atomic_load(src + tid + m * 512, __ATOMIC_RELAXED,
                                 __HIP_MEMORY_SCOPE_AGENT);
#pragma unroll
      for (int m = 0; m < 8; ++m) {
        int jj = tid + m * 512;
        int row = jj >> 7;                 // batch row 0..31 (128 u64/row)
        int cb = (jj & 127) * 8;           // byte col within 1KB row
        *reinterpret_cast<ull*>(&hlds[par][row * 1024 + (cb ^ ((row & 7) << 4))]) = d[m];
      }
    }
    __syncthreads();   // bar1: staged + all waves past poll

    // ---- h-part MFMAs from swizzled LDS (both batch halves) ----
    floatx4 a0 = {0.f, 0.f, 0.f, 0.f};
    floatx4 a1 = {0.f, 0.f, 0.f, 0.f};
    {
      const int r0 = n16, r1 = 16 + n16;
      const int sw0 = (r0 & 7) << 4, sw1 = (r1 & 7) << 4;
#pragma unroll
      for (int kb = 0; kb < 16; ++kb) {
        int cb = kb * 64 + quad * 16;
        short8 f0 = *reinterpret_cast<const short8*>(&hlds[par][r0 * 1024 + (cb ^ sw0)]);
        short8 f1 = *reinterpret_cast<const short8*>(&hlds[par][r1 * 1024 + (cb ^ sw1)]);
        a0 = __builtin_amdgcn_mfma_f32_16x16x32_bf16(whh_r[kb], f0, a0, 0, 0, 0);
        a1 = __builtin_amdgcn_mfma_f32_16x16x32_bf16(whh_r[kb], f1, a1, 0, 0, 0);
      }
    }

    // ---- elementwise: lane owns all 4 gates of (batch, ecol), both halves ----
    float h0v, h1v;
    {
      float pi = x0[0] + a0[0] + b_i;
      float pf = x0[1] + a0[1] + b_f;
      float pg = x0[2] + a0[2] + b_g;
      float po = x0[3] + a0[3] + b_o;
      float ig = 1.f / (1.f + __expf(-pi));
      float fg = 1.f / (1.f + __expf(-pf));
      float eg = __expf(2.f * pg);
      float gg = 1.f - 2.f / (eg + 1.f);
      float og = 1.f / (1.f + __expf(-po));
      c_v0 = fg * c_v0 + ig * gg;
      float ec = __expf(2.f * c_v0);
      h0v = og * (1.f - 2.f / (ec + 1.f));
    }
    {
      float pi = x1[0] + a1[0] + b_i;
      float pf = x1[1] + a1[1] + b_f;
      float pg = x1[2] + a1[2] + b_g;
      float po = x1[3] + a1[3] + b_o;
      float ig = 1.f / (1.f + __expf(-pi));
      float fg = 1.f / (1.f + __expf(-pf));
      float eg = __expf(2.f * pg);
      float gg = 1.f - 2.f / (eg + 1.f);
      float og = 1.f / (1.f + __expf(-po));
      c_v1 = fg * c_v1 + ig * gg;
      float ec = __expf(2.f * c_v1);
      h1v = og * (1.f - 2.f / (ec + 1.f));
    }
    h_l0 = h0v; h_l1 = h1v;

    // ---- publish h(t+1): packed u32 (cols quad,quad+1) per even-quad lane ----
    const int par1 = par ^ 1;
    {
      unsigned hu0 = (unsigned)f2bf(h0v);
      unsigned hu1 = (unsigned)f2bf(h1v);
      unsigned hp0 = (unsigned)__shfl_xor((int)hu0, 16);  // quad^1 -> col+1
      unsigned hp1 = (unsigned)__shfl_xor((int)hu1, 16);
      if (!(quad & 1)) {
        unsigned cp = (unsigned)(g * 16 + wave * 2 + (quad >> 1));
        __hip_atomic_store(&hgu[(size_t)par1 * HU32 + n16 * 256 + cp],
                           hu0 | (hp0 << 16), __ATOMIC_RELAXED,
                           __HIP_MEMORY_SCOPE_AGENT);
        __hip_atomic_store(&hgu[(size_t)par1 * HU32 + (16 + n16) * 256 + cp],
                           hu1 | (hp1 << 16), __ATOMIC_RELAXED,
                           __HIP_MEMORY_SCOPE_AGENT);
      }
    }
    __syncthreads();   // bar2: implicit vmcnt(0) drain of ALL waves' publishes
    if (tid == 0)
      __hip_atomic_store(&flags[g], (unsigned)(t + 1), __ATOMIC_RELAXED,
                         __HIP_MEMORY_SCOPE_AGENT);

    // ---- out[t]: gather 4 cols to quad0 lanes, float4 store per half ----
    {
      float u1 = __shfl_xor(h0v, 16), u2 = __shfl_xor(h0v, 32), u3 = __shfl_xor(u1, 32);
      float v1 = __shfl_xor(h1v, 16), v2 = __shfl_xor(h1v, 32), v3 = __shfl_xor(v1, 32);
      if (quad == 0) {
        const int cb = g * SLICE + wave * 4;
        *reinterpret_cast<float4*>(out + (size_t)t * (BATCH * HID) + n16 * HID + cb) =
            make_float4(h0v, u1, u2, u3);
        *reinterpret_cast<float4*>(out + (size_t)t * (BATCH * HID) + (16 + n16) * HID + cb) =
            make_float4(h1v, v1, v2, v3);
      }
    }

    // ---- x-part for t+1 (off the rendezvous critical path) ----
    const int tt = (t + 1 < T_STEPS) ? t + 1 : t;
    floatx4 xn0, xn1;
    xpart2<XB>(x, xb, tt, n16, quad, wih_r, xn0, xn1);
    x0 = xn0; x1 = xn1;
  }

  // tails: h_n, c_n
  out[(size_t)T_STEPS * BATCH * HID + n16 * HID + ecol] = h_l0;
  out[(size_t)T_STEPS * BATCH * HID + (16 + n16) * HID + ecol] = h_l1;
  out[(size_t)T_STEPS * BATCH * HID + BATCH * HID + n16 * HID + ecol] = c_v0;
  out[(size_t)T_STEPS * BATCH * HID + BATCH * HID + (16 + n16) * HID + ecol] = c_v1;
}

extern "C" void kernel_launch(void* const* d_in, const int* in_sizes, int n_in,
                              void* d_out, int out_size, void* d_ws, size_t ws_size,
                              hipStream_t stream) {
  const float* x = (const float*)d_in[0];
  const float* h0 = (const float*)d_in[1];
  const float* c0 = (const float*)d_in[2];
  const float* w_ih = (const float*)d_in[3];
  const float* b_ih = (const float*)d_in[4];
  const float* w_hh = (const float*)d_in[5];
  const float* b_hh = (const float*)d_in[6];
  float* out = (float*)d_out;
  char* ws = (char*)d_ws;

  // workspace layout
  unsigned* flags = (unsigned*)ws;                        // 64 B
  float* bias = (float*)(ws + 1024);                      // 8 KB
  ushort* wihb = (ushort*)(ws + (16 << 10));              // 2 MB
  ushort* whhb = (ushort*)(ws + (16 << 10) + (2 << 20));  // 2 MB
  unsigned* hgu = (unsigned*)(ws + (16 << 10) + (4 << 20));  // 64 KB (2 h buffers)
  ushort* xb = (ushort*)(ws + (8 << 20));                 // 64 MB (optional)
  const size_t xb_bytes = (size_t)T_STEPS * BATCH * DIN * sizeof(ushort);
  const bool use_xb = ws_size >= ((size_t)(8 << 20) + xb_bytes);

  hipLaunchKernelGGL(prep_kernel, dim3(4096), dim3(256), 0, stream,
                     w_ih, w_hh, b_ih, b_hh, h0, wihb, whhb, bias, hgu, flags);

  if (use_xb) {
    hipLaunchKernelGGL(cvtx_kernel, dim3(8192), dim3(256), 0, stream, x, xb);
    void* args[] = {(void*)&x, (void*)&xb, (void*)&c0, (void*)&wihb, (void*)&whhb,
                    (void*)&bias, (void*)&hgu, (void*)&flags, (void*)&out};
    hipError_t e = hipLaunchCooperativeKernel(
        reinterpret_cast<void*>(&lstm_kernel<true>), dim3(NWG), dim3(THREADS),
        args, 0, stream);
    if (e != hipSuccess) {
      // 16 blocks at 1 block/CU on 256 CUs: unconditionally co-resident.
      hipLaunchKernelGGL(lstm_kernel<true>, dim3(NWG), dim3(THREADS), 0, stream,
                         x, xb, c0, wihb, whhb, bias, hgu, flags, out);
    }
  } else {
    void* args[] = {(void*)&x, (void*)&xb, (void*)&c0, (void*)&wihb, (void*)&whhb,
                    (void*)&bias, (void*)&hgu, (void*)&flags, (void*)&out};
    hipError_t e = hipLaunchCooperativeKernel(
        reinterpret_cast<void*>(&lstm_kernel<false>), dim3(NWG), dim3(THREADS),
        args, 0, stream);
    if (e != hipSuccess) {
      hipLaunchKernelGGL(lstm_kernel<false>, dim3(NWG), dim3(THREADS), 0, stream,
                         x, xb, c0, wihb, whhb, bias, hgu, flags, out);
    }
  }
}